// Round 1
// baseline (8033.758 us; speedup 1.0000x reference)
//
#include <hip/hip_runtime.h>
#include <hip/hip_bf16.h>

#define N_NODES 50000
#define N_EDGES 800000
#define DIM 128
#define NLAYERS 4
#define BN_EPS 1e-5f
#define ECH 64   // edges per block in edge passes

typedef unsigned short bf16_t;

__device__ __forceinline__ float bf2f(bf16_t x) {
    unsigned int u = ((unsigned int)x) << 16;
    return __uint_as_float(u);
}
__device__ __forceinline__ bf16_t f2bf(float f) {
    unsigned int u = __float_as_uint(f);
    unsigned int r = (u + 0x7FFFu + ((u >> 16) & 1u)) >> 16;  // round-nearest-even
    return (bf16_t)r;
}

// ---- 5 node projections: A,B,U,Vf,Vb = h @ W^T + b  (bf16 out) ----
__global__ __launch_bounds__(128) void node_gemm(
    const float* __restrict__ h,
    const float* __restrict__ WA, const float* __restrict__ bA,
    const float* __restrict__ WB, const float* __restrict__ bB,
    const float* __restrict__ WU, const float* __restrict__ bU,
    const float* __restrict__ WVf, const float* __restrict__ bVf,
    const float* __restrict__ WVb, const float* __restrict__ bVb,
    bf16_t* __restrict__ A, bf16_t* __restrict__ B, bf16_t* __restrict__ U,
    bf16_t* __restrict__ Vf, bf16_t* __restrict__ Vb)
{
    __shared__ float hl[8][DIM];
    const int t = threadIdx.x;
    const long n0 = (long)blockIdx.x * 8;
    #pragma unroll
    for (int i = 0; i < 8; ++i) hl[i][t] = h[(n0 + i) * DIM + t];
    __syncthreads();

    const float* Ws[5] = {WA, WB, WU, WVf, WVb};
    const float* bs[5] = {bA, bB, bU, bVf, bVb};
    float acc[5][8];
    #pragma unroll
    for (int m = 0; m < 5; ++m) {
        float bv = bs[m][t];
        #pragma unroll
        for (int n = 0; n < 8; ++n) acc[m][n] = bv;
    }
    const float4* wr[5];
    #pragma unroll
    for (int m = 0; m < 5; ++m) wr[m] = (const float4*)(Ws[m] + (size_t)t * DIM);

    #pragma unroll 4
    for (int j4 = 0; j4 < DIM / 4; ++j4) {
        float4 h4[8];
        #pragma unroll
        for (int n = 0; n < 8; ++n) h4[n] = ((const float4*)hl[n])[j4];
        #pragma unroll
        for (int m = 0; m < 5; ++m) {
            float4 w = wr[m][j4];
            #pragma unroll
            for (int n = 0; n < 8; ++n)
                acc[m][n] += w.x * h4[n].x + w.y * h4[n].y + w.z * h4[n].z + w.w * h4[n].w;
        }
    }
    bf16_t* Os[5] = {A, B, U, Vf, Vb};
    #pragma unroll
    for (int m = 0; m < 5; ++m)
        #pragma unroll
        for (int n = 0; n < 8; ++n)
            Os[m][(n0 + n) * DIM + t] = f2bf(acc[m][n]);
}

// ---- C = e @ WC^T + bC  (bf16 out) ----
__global__ __launch_bounds__(128) void edge_gemm(
    const float* __restrict__ e, const float* __restrict__ WC,
    const float* __restrict__ bC, bf16_t* __restrict__ C)
{
    __shared__ float el[8][DIM];
    const int t = threadIdx.x;
    const long k0 = (long)blockIdx.x * 8;
    #pragma unroll
    for (int i = 0; i < 8; ++i) el[i][t] = e[(k0 + i) * DIM + t];
    __syncthreads();

    float acc[8];
    const float bv = bC[t];
    #pragma unroll
    for (int n = 0; n < 8; ++n) acc[n] = bv;
    const float4* wr = (const float4*)(WC + (size_t)t * DIM);
    #pragma unroll 4
    for (int j4 = 0; j4 < DIM / 4; ++j4) {
        float4 w = wr[j4];
        #pragma unroll
        for (int n = 0; n < 8; ++n) {
            float4 h4 = ((const float4*)el[n])[j4];
            acc[n] += w.x * h4.x + w.y * h4.y + w.z * h4.z + w.w * h4.w;
        }
    }
    #pragma unroll
    for (int n = 0; n < 8; ++n) C[(k0 + n) * DIM + t] = f2bf(acc[n]);
}

// ---- edge BN stats for both gates (sum & sumsq per feature) ----
__global__ __launch_bounds__(128) void edge_stats(
    const int* __restrict__ s0, const int* __restrict__ s1,
    const bf16_t* __restrict__ A, const bf16_t* __restrict__ B,
    const bf16_t* __restrict__ C, float* __restrict__ stats)
{
    __shared__ int ls0[ECH], ls1[ECH];
    const int t = threadIdx.x;
    const long k0 = (long)blockIdx.x * ECH;
    if (t < ECH) { ls0[t] = s0[k0 + t]; ls1[t] = s1[k0 + t]; }
    __syncthreads();

    float sf = 0.f, ssf = 0.f, sb = 0.f, ssb = 0.f;
    for (int i = 0; i < ECH; ++i) {
        const long k = k0 + i;
        const long a = ls0[i], b = ls1[i];
        float c  = bf2f(C[k * DIM + t]);
        float a0 = bf2f(A[a * DIM + t]);
        float b1 = bf2f(B[b * DIM + t]);
        float a1 = bf2f(A[b * DIM + t]);
        float b0 = bf2f(B[a * DIM + t]);
        float tf = a0 + b1 + c;
        float tb = a1 + b0 + c;
        sf += tf; ssf += tf * tf;
        sb += tb; ssb += tb * tb;
    }
    atomicAdd(&stats[t], sf);
    atomicAdd(&stats[128 + t], ssf);
    atomicAdd(&stats[256 + t], sb);
    atomicAdd(&stats[384 + t], ssb);
}

__global__ void finalize_edge_stats(float* __restrict__ stats)
{
    const int t = threadIdx.x;
    const float inv = 1.0f / (float)N_EDGES;
    if (t < 128) {
        float mu = stats[t] * inv;
        float var = stats[128 + t] * inv - mu * mu;
        stats[768 + t] = mu;
        stats[896 + t] = rsqrtf(var + BN_EPS);
    } else {
        int d = t - 128;
        float mu = stats[256 + d] * inv;
        float var = stats[384 + d] * inv - mu * mu;
        stats[1024 + d] = mu;
        stats[1152 + d] = rsqrtf(var + BN_EPS);
    }
}

// ---- fused edge apply: e_new (fwd gate), both gate weights, single scatter ----
__global__ __launch_bounds__(128) void edge_apply(
    const int* __restrict__ s0, const int* __restrict__ s1,
    const bf16_t* __restrict__ A, const bf16_t* __restrict__ B,
    const bf16_t* __restrict__ C,
    const bf16_t* __restrict__ Vf, const bf16_t* __restrict__ Vb,
    const float* __restrict__ stats,
    const float* __restrict__ gne, const float* __restrict__ bne,
    float* __restrict__ ebuf, float* __restrict__ agg)
{
    __shared__ int ls0[ECH], ls1[ECH];
    const int t = threadIdx.x;
    const long k0 = (long)blockIdx.x * ECH;
    if (t < ECH) { ls0[t] = s0[k0 + t]; ls1[t] = s1[k0 + t]; }
    __syncthreads();

    const float g = gne[t], bb = bne[t];
    const float af = stats[896 + t] * g;
    const float cf = bb - stats[768 + t] * af;
    const float ab = stats[1152 + t] * g;
    const float cb = bb - stats[1024 + t] * ab;

    for (int i = 0; i < ECH; ++i) {
        const long k = k0 + i;
        const long sa = ls0[i], sd = ls1[i];
        float c  = bf2f(C[k * DIM + t]);
        float a0 = bf2f(A[sa * DIM + t]);
        float b1 = bf2f(B[sd * DIM + t]);
        float a1 = bf2f(A[sd * DIM + t]);
        float b0 = bf2f(B[sa * DIM + t]);
        float ek = ebuf[k * DIM + t];

        float nf = fmaxf((a0 + b1 + c) * af + cf, 0.0f) + ek;  // new e (fwd gate)
        float nb = fmaxf((a1 + b0 + c) * ab + cb, 0.0f) + ek;
        ebuf[k * DIM + t] = nf;

        float sigf = 1.0f / (1.0f + __expf(-nf));
        float sigb = 1.0f / (1.0f + __expf(-nb));
        float wf = sigf / (sigf + 1e-6f);
        float wb = sigb / (sigb + 1e-6f);
        float msg = bf2f(Vf[sa * DIM + t]) * wf + bf2f(Vb[sa * DIM + t]) * wb;
        atomicAdd(&agg[sd * DIM + t], msg);
    }
}

// ---- node BN stats over (agg + U) ----
__global__ __launch_bounds__(128) void node_stats(
    const float* __restrict__ agg, const bf16_t* __restrict__ U,
    float* __restrict__ stats)
{
    const int t = threadIdx.x;
    const long n0 = (long)blockIdx.x * 50;
    float s = 0.f, ss = 0.f;
    for (int i = 0; i < 50; ++i) {
        const long n = n0 + i;
        float v = agg[n * DIM + t] + bf2f(U[n * DIM + t]);
        s += v; ss += v * v;
    }
    atomicAdd(&stats[512 + t], s);
    atomicAdd(&stats[640 + t], ss);
}

__global__ void finalize_node_stats(float* __restrict__ stats)
{
    const int t = threadIdx.x;
    const float inv = 1.0f / (float)N_NODES;
    float mu = stats[512 + t] * inv;
    float var = stats[640 + t] * inv - mu * mu;
    stats[1280 + t] = mu;
    stats[1408 + t] = rsqrtf(var + BN_EPS);
}

// ---- h_new = relu(bn(agg+U)) + h, in place ----
__global__ __launch_bounds__(256) void node_apply(
    const float* __restrict__ agg, const bf16_t* __restrict__ U,
    const float* __restrict__ stats,
    const float* __restrict__ gh, const float* __restrict__ bh,
    float* __restrict__ hbuf)
{
    const long i = (long)blockIdx.x * 256 + threadIdx.x;
    const int d = (int)(i & (DIM - 1));
    float v = agg[i] + bf2f(U[i]);
    float n = (v - stats[1280 + d]) * stats[1408 + d] * gh[d] + bh[d];
    hbuf[i] = fmaxf(n, 0.0f) + hbuf[i];
}

extern "C" void kernel_launch(void* const* d_in, const int* in_sizes, int n_in,
                              void* d_out, int out_size, void* d_ws, size_t ws_size,
                              hipStream_t stream)
{
    const int* ei = (const int*)d_in[0];
    const int* s0 = ei;
    const int* s1 = ei + N_EDGES;
    const float* h0 = (const float*)d_in[1];
    const float* e0 = (const float*)d_in[2];
    const float* WA = (const float*)d_in[3];  const float* bA = (const float*)d_in[4];
    const float* WB = (const float*)d_in[5];  const float* bB = (const float*)d_in[6];
    const float* WC = (const float*)d_in[7];  const float* bC = (const float*)d_in[8];
    const float* WU = (const float*)d_in[9];  const float* bU = (const float*)d_in[10];
    const float* WVf = (const float*)d_in[11]; const float* bVf = (const float*)d_in[12];
    const float* WVb = (const float*)d_in[13]; const float* bVb = (const float*)d_in[14];
    const float* bnh_g = (const float*)d_in[15]; const float* bnh_b = (const float*)d_in[16];
    const float* bne_g = (const float*)d_in[17]; const float* bne_b = (const float*)d_in[18];

    float* hbuf = (float*)d_out;                       // N*D f32 (live h)
    float* ebuf = hbuf + (size_t)N_NODES * DIM;        // E*D f32 (live e)

    float* agg = (float*)d_ws;                         // N*D f32
    float* stats = agg + (size_t)N_NODES * DIM;        // 2048 f32
    bf16_t* Abuf  = (bf16_t*)(stats + 2048);
    bf16_t* Bbuf  = Abuf  + (size_t)N_NODES * DIM;
    bf16_t* Ubuf  = Bbuf  + (size_t)N_NODES * DIM;
    bf16_t* Vfbuf = Ubuf  + (size_t)N_NODES * DIM;
    bf16_t* Vbbuf = Vfbuf + (size_t)N_NODES * DIM;
    bf16_t* Cbuf  = Vbbuf + (size_t)N_NODES * DIM;     // E*D bf16

    hipMemcpyAsync(hbuf, h0, (size_t)N_NODES * DIM * sizeof(float),
                   hipMemcpyDeviceToDevice, stream);
    hipMemcpyAsync(ebuf, e0, (size_t)N_EDGES * DIM * sizeof(float),
                   hipMemcpyDeviceToDevice, stream);

    for (int l = 0; l < NLAYERS; ++l) {
        const size_t wo = (size_t)l * DIM * DIM;
        const size_t bo = (size_t)l * DIM;
        // zero agg + the 6 sum arrays (first 768 floats of stats)
        hipMemsetAsync(agg, 0, ((size_t)N_NODES * DIM + 768) * sizeof(float), stream);

        node_gemm<<<N_NODES / 8, 128, 0, stream>>>(
            hbuf, WA + wo, bA + bo, WB + wo, bB + bo, WU + wo, bU + bo,
            WVf + wo, bVf + bo, WVb + wo, bVb + bo,
            Abuf, Bbuf, Ubuf, Vfbuf, Vbbuf);
        edge_gemm<<<N_EDGES / 8, 128, 0, stream>>>(ebuf, WC + wo, bC + bo, Cbuf);
        edge_stats<<<N_EDGES / ECH, 128, 0, stream>>>(s0, s1, Abuf, Bbuf, Cbuf, stats);
        finalize_edge_stats<<<1, 256, 0, stream>>>(stats);
        edge_apply<<<N_EDGES / ECH, 128, 0, stream>>>(
            s0, s1, Abuf, Bbuf, Cbuf, Vfbuf, Vbbuf, stats,
            bne_g + bo, bne_b + bo, ebuf, agg);
        node_stats<<<N_NODES / 50, 128, 0, stream>>>(agg, Ubuf, stats);
        finalize_node_stats<<<1, 128, 0, stream>>>(stats);
        node_apply<<<(N_NODES * DIM) / 256, 256, 0, stream>>>(
            agg, Ubuf, stats, bnh_g + bo, bnh_b + bo, hbuf);
    }
}